// Round 1
// baseline (398.209 us; speedup 1.0000x reference)
//
#include <hip/hip_runtime.h>
#include <hip/hip_bf16.h>
#include <math.h>

// Multi-head self-attention w/ RoPE, causal. B=2, S=2048, H=16, hd=64, D=1024.
// fp32 inputs -> bf16 ws -> qkv GEMMs (V stored transposed) -> RoPE (Q pre-scaled
// by 1/8) -> barrier-free flash attention (defer-max softmax, l via ones-MFMA) ->
// oproj -> fp32 output.
// ws: xb(8MB) wq/wk/wv/wo(2MB ea) q,k,vT(8MB ea) attn_out(8MB) = 48MB.

#define S_LEN 2048
#define NHEADS 16
#define HD 64
#define DM 1024

typedef __attribute__((ext_vector_type(8))) short bf16x8;  // MFMA A/B frag (4 VGPRs)
typedef __attribute__((ext_vector_type(4))) float f32x4;   // MFMA C/D frag

#define MFMA16(a, b, c) __builtin_amdgcn_mfma_f32_16x16x32_bf16((a), (b), (c), 0, 0, 0)
#define NEG_BIG (-1e30f)  // finite mask sentinel

// ---------------------------------------------------------------------------
// fp32 -> bf16 conversion pre-pass.
// ---------------------------------------------------------------------------
__global__ __launch_bounds__(256) void convert_kernel(
    const float* __restrict__ x,  const float* __restrict__ wq,
    const float* __restrict__ wk, const float* __restrict__ wv,
    const float* __restrict__ wo,
    __hip_bfloat16* __restrict__ xb,  __hip_bfloat16* __restrict__ wqb,
    __hip_bfloat16* __restrict__ wkb, __hip_bfloat16* __restrict__ wvb,
    __hip_bfloat16* __restrict__ wob)
{
    const int y = blockIdx.y;
    const float* src;
    __hip_bfloat16* dst;
    size_t off = 0;
    if (y < 4)      { src = x;  dst = xb;  off = (size_t)y * 1048576; }
    else if (y == 4) { src = wq; dst = wqb; }
    else if (y == 5) { src = wk; dst = wkb; }
    else if (y == 6) { src = wv; dst = wvb; }
    else             { src = wo; dst = wob; }

    const size_t i = off + ((size_t)blockIdx.x * 256 + threadIdx.x) * 4;
    float4 v = *(const float4*)(src + i);
    __hip_bfloat16 t[4] = { __float2bfloat16(v.x), __float2bfloat16(v.y),
                            __float2bfloat16(v.z), __float2bfloat16(v.w) };
    *(ushort4*)(dst + i) = *(ushort4*)t;
}

// ---------------------------------------------------------------------------
// GEMM: C[m,n] = sum_k A[m,k] * W[n,k]. 128x128 tile, BK=32, 4 waves 2x2.
// z=0,1 (Q,K): out (B,H,S,hd).  z=2 (V): out TRANSPOSED (B,H,hd,S) so the
// attention PV B-operand loads contiguously from global.
// ---------------------------------------------------------------------------
__global__ __launch_bounds__(256) void qkv_kernel(
    const __hip_bfloat16* __restrict__ X,
    const __hip_bfloat16* __restrict__ Wq,
    const __hip_bfloat16* __restrict__ Wk,
    const __hip_bfloat16* __restrict__ Wv,
    __hip_bfloat16* __restrict__ qws,
    __hip_bfloat16* __restrict__ kws,
    __hip_bfloat16* __restrict__ vws)
{
    const int z = blockIdx.z;
    const __hip_bfloat16* __restrict__ W = (z == 0) ? Wq : (z == 1) ? Wk : Wv;
    __hip_bfloat16* __restrict__ out = (z == 0) ? qws : (z == 1) ? kws : vws;

    constexpr int LDK = 40;
    __shared__ __align__(16) __hip_bfloat16 Asm[128 * LDK];
    __shared__ __align__(16) __hip_bfloat16 Bsm[128 * LDK];

    const int tid = threadIdx.x;
    const int wave = tid >> 6, lane = tid & 63;
    const int quad = lane >> 4, l15 = lane & 15;
    const int wm = (wave >> 1) * 64, wn = (wave & 1) * 64;
    const int m0 = blockIdx.y * 128, n0 = blockIdx.x * 128;

    f32x4 acc[4][4] = {};

    for (int k0 = 0; k0 < DM; k0 += 32) {
#pragma unroll
        for (int c = 0; c < 2; c++) {
            int idx = c * 2048 + tid * 8;
            int r = idx >> 5, kc = idx & 31;
            *(int4*)(&Asm[r * LDK + kc]) = *(const int4*)(X + (size_t)(m0 + r) * DM + k0 + kc);
            *(int4*)(&Bsm[r * LDK + kc]) = *(const int4*)(W + (size_t)(n0 + r) * DM + k0 + kc);
        }
        __syncthreads();
        bf16x8 af[4], bfv[4];
#pragma unroll
        for (int i = 0; i < 4; i++)
            af[i] = *(const bf16x8*)(&Asm[(wm + i * 16 + l15) * LDK + quad * 8]);
#pragma unroll
        for (int j = 0; j < 4; j++)
            bfv[j] = *(const bf16x8*)(&Bsm[(wn + j * 16 + l15) * LDK + quad * 8]);
#pragma unroll
        for (int i = 0; i < 4; i++)
#pragma unroll
            for (int j = 0; j < 4; j++)
                acc[i][j] = MFMA16(af[i], bfv[j], acc[i][j]);
        __syncthreads();
    }

#pragma unroll
    for (int i = 0; i < 4; i++) {
#pragma unroll
        for (int r = 0; r < 4; r++) {
            int m = m0 + wm + i * 16 + quad * 4 + r;
            int b = m >> 11, s = m & 2047;
#pragma unroll
            for (int j = 0; j < 4; j++) {
                int col = n0 + wn + j * 16 + l15;
                int h = col >> 6, d = col & 63;
                size_t idx = (z == 2)
                    ? (((size_t)(b * NHEADS + h)) * HD + d) * S_LEN + s    // V^T: (B,H,hd,S)
                    : (((size_t)(b * NHEADS + h)) * S_LEN + s) * HD + d;   // Q,K: (B,H,S,hd)
                out[idx] = __float2bfloat16(acc[i][j][r]);
            }
        }
    }
}

// ---------------------------------------------------------------------------
// RoPE in-place on q,k laid out (B,H,S,hd). Q additionally pre-scaled by
// 1/sqrt(hd)=0.125 (exact in bf16: power of 2) so attn skips per-score scaling.
// ---------------------------------------------------------------------------
__global__ __launch_bounds__(256) void rope_kernel(
    __hip_bfloat16* __restrict__ q, __hip_bfloat16* __restrict__ k)
{
    __hip_bfloat16* __restrict__ p = (blockIdx.y == 0) ? q : k;
    const float qscale = (blockIdx.y == 0) ? 0.125f : 1.0f;
    const int gid = blockIdx.x * 256 + threadIdx.x;       // [0, 524288)
    const int e0 = gid * 8;
    const int s = (gid >> 3) & 2047;
    const int d0 = (gid & 7) * 8;

    int4 raw = *(const int4*)(p + e0);
    __hip_bfloat16* v = (__hip_bfloat16*)&raw;
#pragma unroll
    for (int i = 0; i < 4; i++) {
        int pi = (d0 >> 1) + i;
        float theta = powf(10000.0f, -(float)(2 * pi) * (1.0f / 64.0f));
        float sn, cs;
        sincosf((float)s * theta, &sn, &cs);
        float x1 = __bfloat162float(v[2 * i]);
        float x2 = __bfloat162float(v[2 * i + 1]);
        v[2 * i]     = __float2bfloat16((x1 * cs - x2 * sn) * qscale);
        v[2 * i + 1] = __float2bfloat16((x1 * sn + x2 * cs) * qscale);
    }
    *(int4*)(p + e0) = raw;
}

// ---------------------------------------------------------------------------
// Barrier-free flash attention. Block = 4 independent waves, 16 q-rows each.
// One block per 64-row q-tile (grid.x=32, qi = 31-bx so big tiles launch
// first): 1024 blocks -> 4 blocks/CU -> 4 waves/SIMD to hide the serial
// softmax chain. Off-diagonal kv-iters carry no mask code (diag peeled).
// Softmax: defer-max (THR=8) skips the cross-lane max reduce + O/l rescale
// in the common path; l accumulated via an extra MFMA against a ones-frag
// (row-sum lands in the C fragment) instead of a shuffle-reduce chain.
// K register-double-buffered; V^T frags loaded straight from global; the P
// C-layout -> A-layout transform goes through a WAVE-PRIVATE LDS region.
// ---------------------------------------------------------------------------
__global__ __launch_bounds__(256) void attn_kernel(
    const __hip_bfloat16* __restrict__ Qg,
    const __hip_bfloat16* __restrict__ Kg,
    const __hip_bfloat16* __restrict__ Vtg,  // (B,H,hd,S)
    __hip_bfloat16* __restrict__ Og)         // (B,S,D)
{
    const int bh = blockIdx.y;
    const int tid = threadIdx.x;
    const int w = tid >> 6, lane = tid & 63;
    const int quad = lane >> 4, l15 = lane & 15;
    const size_t base = (size_t)bh * S_LEN * HD;
    const __hip_bfloat16* Qb = Qg + base;
    const __hip_bfloat16* Kb = Kg + base;
    const __hip_bfloat16* Vtb = Vtg + base;
    const int b = bh >> 4, h = bh & 15;

    __shared__ __align__(16) __hip_bfloat16 Pl[64 * 72];
    __hip_bfloat16* Prow = &Pl[w * 16 * 72];  // wave-private 16x64(+8 pad)

    const int qi = 31 - blockIdx.x;           // big tiles dispatch first
    const int q0 = qi * 64;
    const int qrow = q0 + w * 16 + l15;

    bf16x8 qf[2];
#pragma unroll
    for (int st = 0; st < 2; st++)
        qf[st] = *(const bf16x8*)(Qb + (size_t)qrow * HD + st * 32 + quad * 8);

    bf16x8 ones;
#pragma unroll
    for (int i = 0; i < 8; i++) ones[i] = (short)0x3F80;  // bf16 1.0

    float m_i[4];
    f32x4 lacc = {};
    f32x4 o[4] = {};
#pragma unroll
    for (int r = 0; r < 4; r++) m_i[r] = NEG_BIG;

    // prefetch K tile 0
    bf16x8 kf[2][4];
#pragma unroll
    for (int st = 0; st < 2; st++)
#pragma unroll
        for (int t = 0; t < 4; t++)
            kf[st][t] = *(const bf16x8*)(Kb + (size_t)(t * 16 + l15) * HD + st * 32 + quad * 8);

    // ---- off-diagonal kv tiles: no causal masking needed ----
#pragma unroll 1
    for (int j = 0; j < qi; j++) {
        const int kv0 = j * 64;

        // issue V^T frag loads early (used after softmax)
        bf16x8 vf[2][4];
#pragma unroll
        for (int st = 0; st < 2; st++)
#pragma unroll
            for (int t = 0; t < 4; t++)
                vf[st][t] = *(const bf16x8*)(Vtb + (size_t)(t * 16 + l15) * S_LEN + kv0 + st * 32 + quad * 8);

        // S = Q K^T with current K frags (Q pre-scaled by 1/8)
        f32x4 sc[4] = {};
#pragma unroll
        for (int st = 0; st < 2; st++)
#pragma unroll
            for (int t = 0; t < 4; t++)
                sc[t] = MFMA16(qf[st], kf[st][t], sc[t]);

        // prefetch next K tile
        bf16x8 kfn[2][4];
#pragma unroll
        for (int st = 0; st < 2; st++)
#pragma unroll
            for (int t = 0; t < 4; t++)
                kfn[st][t] = *(const bf16x8*)(Kb + (size_t)(kv0 + 64 + t * 16 + l15) * HD + st * 32 + quad * 8);

        // defer-max online softmax
        float pm[4];
#pragma unroll
        for (int r = 0; r < 4; r++)
            pm[r] = fmaxf(fmaxf(sc[0][r], sc[1][r]), fmaxf(sc[2][r], sc[3][r]));
        bool ok = true;
#pragma unroll
        for (int r = 0; r < 4; r++) ok = ok && (pm[r] <= m_i[r] + 8.0f);
        if (!__all(ok)) {
#pragma unroll
            for (int off = 1; off < 16; off <<= 1)
#pragma unroll
                for (int r = 0; r < 4; r++) pm[r] = fmaxf(pm[r], __shfl_xor(pm[r], off));
#pragma unroll
            for (int r = 0; r < 4; r++) {
                float mn = fmaxf(m_i[r], pm[r]);
                float al = __expf(m_i[r] - mn);
                m_i[r] = mn;
                lacc[r] *= al;
#pragma unroll
                for (int t = 0; t < 4; t++) o[t][r] *= al;
            }
        }

        // P = exp(S - m), C layout -> A-operand layout via wave-private LDS
#pragma unroll
        for (int t = 0; t < 4; t++)
#pragma unroll
            for (int r = 0; r < 4; r++)
                Prow[(quad * 4 + r) * 72 + t * 16 + l15] =
                    __float2bfloat16(__expf(sc[t][r] - m_i[r]));

        // O += P V ; l += P @ ones (row-sum via MFMA, no shuffle chain)
#pragma unroll
        for (int st = 0; st < 2; st++) {
            bf16x8 pf = *(const bf16x8*)(&Prow[l15 * 72 + st * 32 + quad * 8]);
            lacc = MFMA16(pf, ones, lacc);
#pragma unroll
            for (int t = 0; t < 4; t++)
                o[t] = MFMA16(pf, vf[st][t], o[t]);
        }

        // rotate K double buffer
#pragma unroll
        for (int st = 0; st < 2; st++)
#pragma unroll
            for (int t = 0; t < 4; t++)
                kf[st][t] = kfn[st][t];
    }

    // ---- diagonal kv tile: causal mask, no prefetch ----
    {
        const int kv0 = qi * 64;

        bf16x8 vf[2][4];
#pragma unroll
        for (int st = 0; st < 2; st++)
#pragma unroll
            for (int t = 0; t < 4; t++)
                vf[st][t] = *(const bf16x8*)(Vtb + (size_t)(t * 16 + l15) * S_LEN + kv0 + st * 32 + quad * 8);

        f32x4 sc[4] = {};
#pragma unroll
        for (int st = 0; st < 2; st++)
#pragma unroll
            for (int t = 0; t < 4; t++)
                sc[t] = MFMA16(qf[st], kf[st][t], sc[t]);

#pragma unroll
        for (int t = 0; t < 4; t++) {
            int col = kv0 + t * 16 + l15;
#pragma unroll
            for (int r = 0; r < 4; r++) {
                int row = q0 + w * 16 + quad * 4 + r;
                if (col > row) sc[t][r] = NEG_BIG;
            }
        }

        float pm[4];
#pragma unroll
        for (int r = 0; r < 4; r++)
            pm[r] = fmaxf(fmaxf(sc[0][r], sc[1][r]), fmaxf(sc[2][r], sc[3][r]));
        bool ok = true;
#pragma unroll
        for (int r = 0; r < 4; r++) ok = ok && (pm[r] <= m_i[r] + 8.0f);
        if (!__all(ok)) {
#pragma unroll
            for (int off = 1; off < 16; off <<= 1)
#pragma unroll
                for (int r = 0; r < 4; r++) pm[r] = fmaxf(pm[r], __shfl_xor(pm[r], off));
#pragma unroll
            for (int r = 0; r < 4; r++) {
                float mn = fmaxf(m_i[r], pm[r]);
                float al = __expf(m_i[r] - mn);
                m_i[r] = mn;
                lacc[r] *= al;
#pragma unroll
                for (int t = 0; t < 4; t++) o[t][r] *= al;
            }
        }

#pragma unroll
        for (int t = 0; t < 4; t++)
#pragma unroll
            for (int r = 0; r < 4; r++)
                Prow[(quad * 4 + r) * 72 + t * 16 + l15] =
                    __float2bfloat16(__expf(sc[t][r] - m_i[r]));

#pragma unroll
        for (int st = 0; st < 2; st++) {
            bf16x8 pf = *(const bf16x8*)(&Prow[l15 * 72 + st * 32 + quad * 8]);
            lacc = MFMA16(pf, ones, lacc);
#pragma unroll
            for (int t = 0; t < 4; t++)
                o[t] = MFMA16(pf, vf[st][t], o[t]);
        }
    }

    // epilogue: O/l -> (B,S,D)
#pragma unroll
    for (int t = 0; t < 4; t++)
#pragma unroll
        for (int r = 0; r < 4; r++) {
            int s = q0 + w * 16 + quad * 4 + r;
            int d = t * 16 + l15;
            float val = o[t][r] / lacc[r];
            Og[((size_t)(b * S_LEN + s)) * DM + h * HD + d] = __float2bfloat16(val);
        }
}

// ---------------------------------------------------------------------------
// Output projection: out = attn @ Wo^T -> d_out as fp32 (bf16-rounded).
// ---------------------------------------------------------------------------
__global__ __launch_bounds__(256) void oproj_kernel(
    const __hip_bfloat16* __restrict__ A,
    const __hip_bfloat16* __restrict__ W,
    float* __restrict__ out)
{
    constexpr int LDK = 40;
    __shared__ __align__(16) __hip_bfloat16 Asm[128 * LDK];
    __shared__ __align__(16) __hip_bfloat16 Bsm[128 * LDK];

    const int tid = threadIdx.x;
    const int wave = tid >> 6, lane = tid & 63;
    const int quad = lane >> 4, l15 = lane & 15;
    const int wm = (wave >> 1) * 64, wn = (wave & 1) * 64;
    const int m0 = blockIdx.y * 128, n0 = blockIdx.x * 128;

    f32x4 acc[4][4] = {};

    for (int k0 = 0; k0 < DM; k0 += 32) {
#pragma unroll
        for (int c = 0; c < 2; c++) {
            int idx = c * 2048 + tid * 8;
            int r = idx >> 5, kc = idx & 31;
            *(int4*)(&Asm[r * LDK + kc]) = *(const int4*)(A + (size_t)(m0 + r) * DM + k0 + kc);
            *(int4*)(&Bsm[r * LDK + kc]) = *(const int4*)(W + (size_t)(n0 + r) * DM + k0 + kc);
        }
        __syncthreads();
        bf16x8 af[4], bfv[4];
#pragma unroll
        for (int i = 0; i < 4; i++)
            af[i] = *(const bf16x8*)(&Asm[(wm + i * 16 + l15) * LDK + quad * 8]);
#pragma unroll
        for (int j = 0; j < 4; j++)
            bfv[j] = *(const bf16x8*)(&Bsm[(wn + j * 16 + l15) * LDK + quad * 8]);
#pragma unroll
        for (int i = 0; i < 4; i++)
#pragma unroll
            for (int j = 0; j < 4; j++)
                acc[i][j] = MFMA16(af[i], bfv[j], acc[i][j]);
        __syncthreads();
    }

#pragma unroll
    for (int i = 0; i < 4; i++)
#pragma unroll
        for (int r = 0; r < 4; r++) {
            int m = m0 + wm + i * 16 + quad * 4 + r;
#pragma unroll
            for (int j = 0; j < 4; j++) {
                int col = n0 + wn + j * 16 + l15;
                __hip_bfloat16 bb = __float2bfloat16(acc[i][j][r]);
                unsigned int u = ((unsigned int)(*(unsigned short*)&bb)) << 16;
                out[(size_t)m * DM + col] = __uint_as_float(u);
            }
        }
}

// ---------------------------------------------------------------------------
extern "C" void kernel_launch(void* const* d_in, const int* in_sizes, int n_in,
                              void* d_out, int out_size, void* d_ws, size_t ws_size,
                              hipStream_t stream)
{
    const float* x  = (const float*)d_in[0];
    const float* wq = (const float*)d_in[1];
    const float* wk = (const float*)d_in[2];
    const float* wv = (const float*)d_in[3];
    const float* wo = (const float*)d_in[4];
    float* out = (float*)d_out;

    const size_t xe = (size_t)2 * S_LEN * DM;
    const size_t we = (size_t)DM * DM;
    __hip_bfloat16* xb  = (__hip_bfloat16*)d_ws;
    __hip_bfloat16* wqb = xb + xe;
    __hip_bfloat16* wkb = wqb + we;
    __hip_bfloat16* wvb = wkb + we;
    __hip_bfloat16* wob = wvb + we;
    __hip_bfloat16* qws = wob + we;
    __hip_bfloat16* kws = qws + xe;
    __hip_bfloat16* vws = kws + xe;   // V^T (B,H,hd,S)
    __hip_bfloat16* aws = vws + xe;

    dim3 blk(256, 1, 1);
    convert_kernel<<<dim3(1024, 8, 1), blk, 0, stream>>>(x, wq, wk, wv, wo,
                                                         xb, wqb, wkb, wvb, wob);
    qkv_kernel<<<dim3(8, 32, 3), blk, 0, stream>>>(xb, wqb, wkb, wvb, qws, kws, vws);
    rope_kernel<<<dim3(2048, 2, 1), blk, 0, stream>>>(qws, kws);
    attn_kernel<<<dim3(32, 32, 1), blk, 0, stream>>>(qws, kws, vws, aws);
    oproj_kernel<<<dim3(8, 32, 1), blk, 0, stream>>>(aws, wob, out);
}

// Round 2
// 303.283 us; speedup vs baseline: 1.3130x; 1.3130x over previous
//
#include <hip/hip_runtime.h>
#include <hip/hip_bf16.h>
#include <math.h>

// Multi-head self-attention w/ RoPE, causal. B=2, S=2048, H=16, hd=64, D=1024.
// fp32 inputs -> bf16 ws -> qkv GEMMs (V stored transposed) -> RoPE (Q pre-scaled
// by 1/8) -> barrier-free flash attention (defer-max softmax, l via ones-MFMA) ->
// oproj -> fp32 output.
// ws: xb(8MB) wq/wk/wv/wo(2MB ea) q,k,vT(8MB ea) attn_out(8MB) = 48MB.

#define S_LEN 2048
#define NHEADS 16
#define HD 64
#define DM 1024

typedef __attribute__((ext_vector_type(8))) short bf16x8;  // MFMA A/B frag (4 VGPRs)
typedef __attribute__((ext_vector_type(4))) float f32x4;   // MFMA C/D frag

#define MFMA16(a, b, c) __builtin_amdgcn_mfma_f32_16x16x32_bf16((a), (b), (c), 0, 0, 0)
#define NEG_BIG (-1e30f)  // finite mask sentinel

// ---------------------------------------------------------------------------
// fp32 -> bf16 conversion pre-pass.
// ---------------------------------------------------------------------------
__global__ __launch_bounds__(256) void convert_kernel(
    const float* __restrict__ x,  const float* __restrict__ wq,
    const float* __restrict__ wk, const float* __restrict__ wv,
    const float* __restrict__ wo,
    __hip_bfloat16* __restrict__ xb,  __hip_bfloat16* __restrict__ wqb,
    __hip_bfloat16* __restrict__ wkb, __hip_bfloat16* __restrict__ wvb,
    __hip_bfloat16* __restrict__ wob)
{
    const int y = blockIdx.y;
    const float* src;
    __hip_bfloat16* dst;
    size_t off = 0;
    if (y < 4)      { src = x;  dst = xb;  off = (size_t)y * 1048576; }
    else if (y == 4) { src = wq; dst = wqb; }
    else if (y == 5) { src = wk; dst = wkb; }
    else if (y == 6) { src = wv; dst = wvb; }
    else             { src = wo; dst = wob; }

    const size_t i = off + ((size_t)blockIdx.x * 256 + threadIdx.x) * 4;
    float4 v = *(const float4*)(src + i);
    __hip_bfloat16 t[4] = { __float2bfloat16(v.x), __float2bfloat16(v.y),
                            __float2bfloat16(v.z), __float2bfloat16(v.w) };
    *(ushort4*)(dst + i) = *(ushort4*)t;
}

// ---------------------------------------------------------------------------
// GEMM: C[m,n] = sum_k A[m,k] * W[n,k]. 128x128 tile, BK=32, 4 waves 2x2.
// z=0,1 (Q,K): out (B,H,S,hd).  z=2 (V): out TRANSPOSED (B,H,hd,S) so the
// attention PV B-operand loads contiguously from global.
// ---------------------------------------------------------------------------
__global__ __launch_bounds__(256) void qkv_kernel(
    const __hip_bfloat16* __restrict__ X,
    const __hip_bfloat16* __restrict__ Wq,
    const __hip_bfloat16* __restrict__ Wk,
    const __hip_bfloat16* __restrict__ Wv,
    __hip_bfloat16* __restrict__ qws,
    __hip_bfloat16* __restrict__ kws,
    __hip_bfloat16* __restrict__ vws)
{
    const int z = blockIdx.z;
    const __hip_bfloat16* __restrict__ W = (z == 0) ? Wq : (z == 1) ? Wk : Wv;
    __hip_bfloat16* __restrict__ out = (z == 0) ? qws : (z == 1) ? kws : vws;

    constexpr int LDK = 40;
    __shared__ __align__(16) __hip_bfloat16 Asm[128 * LDK];
    __shared__ __align__(16) __hip_bfloat16 Bsm[128 * LDK];

    const int tid = threadIdx.x;
    const int wave = tid >> 6, lane = tid & 63;
    const int quad = lane >> 4, l15 = lane & 15;
    const int wm = (wave >> 1) * 64, wn = (wave & 1) * 64;
    const int m0 = blockIdx.y * 128, n0 = blockIdx.x * 128;

    f32x4 acc[4][4] = {};

    for (int k0 = 0; k0 < DM; k0 += 32) {
#pragma unroll
        for (int c = 0; c < 2; c++) {
            int idx = c * 2048 + tid * 8;
            int r = idx >> 5, kc = idx & 31;
            *(int4*)(&Asm[r * LDK + kc]) = *(const int4*)(X + (size_t)(m0 + r) * DM + k0 + kc);
            *(int4*)(&Bsm[r * LDK + kc]) = *(const int4*)(W + (size_t)(n0 + r) * DM + k0 + kc);
        }
        __syncthreads();
        bf16x8 af[4], bfv[4];
#pragma unroll
        for (int i = 0; i < 4; i++)
            af[i] = *(const bf16x8*)(&Asm[(wm + i * 16 + l15) * LDK + quad * 8]);
#pragma unroll
        for (int j = 0; j < 4; j++)
            bfv[j] = *(const bf16x8*)(&Bsm[(wn + j * 16 + l15) * LDK + quad * 8]);
#pragma unroll
        for (int i = 0; i < 4; i++)
#pragma unroll
            for (int j = 0; j < 4; j++)
                acc[i][j] = MFMA16(af[i], bfv[j], acc[i][j]);
        __syncthreads();
    }

#pragma unroll
    for (int i = 0; i < 4; i++) {
#pragma unroll
        for (int r = 0; r < 4; r++) {
            int m = m0 + wm + i * 16 + quad * 4 + r;
            int b = m >> 11, s = m & 2047;
#pragma unroll
            for (int j = 0; j < 4; j++) {
                int col = n0 + wn + j * 16 + l15;
                int h = col >> 6, d = col & 63;
                size_t idx = (z == 2)
                    ? (((size_t)(b * NHEADS + h)) * HD + d) * S_LEN + s    // V^T: (B,H,hd,S)
                    : (((size_t)(b * NHEADS + h)) * S_LEN + s) * HD + d;   // Q,K: (B,H,S,hd)
                out[idx] = __float2bfloat16(acc[i][j][r]);
            }
        }
    }
}

// ---------------------------------------------------------------------------
// RoPE in-place on q,k laid out (B,H,S,hd). Q additionally pre-scaled by
// 1/sqrt(hd)=0.125 (exact in bf16: power of 2) so attn skips per-score scaling.
// ---------------------------------------------------------------------------
__global__ __launch_bounds__(256) void rope_kernel(
    __hip_bfloat16* __restrict__ q, __hip_bfloat16* __restrict__ k)
{
    __hip_bfloat16* __restrict__ p = (blockIdx.y == 0) ? q : k;
    const float qscale = (blockIdx.y == 0) ? 0.125f : 1.0f;
    const int gid = blockIdx.x * 256 + threadIdx.x;       // [0, 524288)
    const int e0 = gid * 8;
    const int s = (gid >> 3) & 2047;
    const int d0 = (gid & 7) * 8;

    int4 raw = *(const int4*)(p + e0);
    __hip_bfloat16* v = (__hip_bfloat16*)&raw;
#pragma unroll
    for (int i = 0; i < 4; i++) {
        int pi = (d0 >> 1) + i;
        float theta = powf(10000.0f, -(float)(2 * pi) * (1.0f / 64.0f));
        float sn, cs;
        sincosf((float)s * theta, &sn, &cs);
        float x1 = __bfloat162float(v[2 * i]);
        float x2 = __bfloat162float(v[2 * i + 1]);
        v[2 * i]     = __float2bfloat16((x1 * cs - x2 * sn) * qscale);
        v[2 * i + 1] = __float2bfloat16((x1 * sn + x2 * cs) * qscale);
    }
    *(int4*)(p + e0) = raw;
}

// ---------------------------------------------------------------------------
// Barrier-free flash attention. Block = 4 independent waves, 16 q-rows each.
// Grid (16, 64): by = (half<<5)|bh, qi = half ? 31-bx : bx. Each block does ONE
// 64-row q-tile. Under round-robin block->CU dispatch (n%256), every CU gets
// blocks {bx, bx, half0/half1 x2} -> per-CU kv-iter total = 2(bx+1)+2(32-bx)
// = 66 for ALL CUs: perfectly balanced AND 4 blocks/CU (16 waves/CU) for
// latency hiding. (Round-1's (32,32) grid clustered same-qi blocks per CU ->
// makespan 128/66 units = the measured 1.7x regression.)
// Softmax: defer-max (THR=8) skips cross-lane max reduce + O/l rescale in the
// common path; l accumulated via ones-MFMA instead of a shuffle-reduce chain.
// K register-double-buffered; V^T frags loaded straight from global; the P
// C-layout -> A-layout transform goes through a WAVE-PRIVATE LDS region.
// s_setprio(1) wraps the MFMA clusters (T5; +4-7% in this independent-wave
// regime per learn_hip m191).
// ---------------------------------------------------------------------------
__global__ __launch_bounds__(256) void attn_kernel(
    const __hip_bfloat16* __restrict__ Qg,
    const __hip_bfloat16* __restrict__ Kg,
    const __hip_bfloat16* __restrict__ Vtg,  // (B,H,hd,S)
    __hip_bfloat16* __restrict__ Og)         // (B,S,D)
{
    const int bh = blockIdx.y & 31;
    const int half = blockIdx.y >> 5;
    const int tid = threadIdx.x;
    const int w = tid >> 6, lane = tid & 63;
    const int quad = lane >> 4, l15 = lane & 15;
    const size_t base = (size_t)bh * S_LEN * HD;
    const __hip_bfloat16* Qb = Qg + base;
    const __hip_bfloat16* Kb = Kg + base;
    const __hip_bfloat16* Vtb = Vtg + base;
    const int b = bh >> 4, h = bh & 15;

    __shared__ __align__(16) __hip_bfloat16 Pl[64 * 72];
    __hip_bfloat16* Prow = &Pl[w * 16 * 72];  // wave-private 16x64(+8 pad)

    const int qi = half ? (31 - blockIdx.x) : blockIdx.x;
    const int q0 = qi * 64;
    const int qrow = q0 + w * 16 + l15;

    bf16x8 qf[2];
#pragma unroll
    for (int st = 0; st < 2; st++)
        qf[st] = *(const bf16x8*)(Qb + (size_t)qrow * HD + st * 32 + quad * 8);

    bf16x8 ones;
#pragma unroll
    for (int i = 0; i < 8; i++) ones[i] = (short)0x3F80;  // bf16 1.0

    float m_i[4];
    f32x4 lacc = {};
    f32x4 o[4] = {};
#pragma unroll
    for (int r = 0; r < 4; r++) m_i[r] = NEG_BIG;

    // prefetch K tile 0
    bf16x8 kf[2][4];
#pragma unroll
    for (int st = 0; st < 2; st++)
#pragma unroll
        for (int t = 0; t < 4; t++)
            kf[st][t] = *(const bf16x8*)(Kb + (size_t)(t * 16 + l15) * HD + st * 32 + quad * 8);

    // ---- off-diagonal kv tiles: no causal masking needed ----
#pragma unroll 1
    for (int j = 0; j < qi; j++) {
        const int kv0 = j * 64;

        // issue V^T frag loads early (used after softmax)
        bf16x8 vf[2][4];
#pragma unroll
        for (int st = 0; st < 2; st++)
#pragma unroll
            for (int t = 0; t < 4; t++)
                vf[st][t] = *(const bf16x8*)(Vtb + (size_t)(t * 16 + l15) * S_LEN + kv0 + st * 32 + quad * 8);

        // S = Q K^T with current K frags (Q pre-scaled by 1/8)
        f32x4 sc[4] = {};
        __builtin_amdgcn_s_setprio(1);
#pragma unroll
        for (int st = 0; st < 2; st++)
#pragma unroll
            for (int t = 0; t < 4; t++)
                sc[t] = MFMA16(qf[st], kf[st][t], sc[t]);
        __builtin_amdgcn_s_setprio(0);

        // prefetch next K tile
        bf16x8 kfn[2][4];
#pragma unroll
        for (int st = 0; st < 2; st++)
#pragma unroll
            for (int t = 0; t < 4; t++)
                kfn[st][t] = *(const bf16x8*)(Kb + (size_t)(kv0 + 64 + t * 16 + l15) * HD + st * 32 + quad * 8);

        // defer-max online softmax
        float pm[4];
#pragma unroll
        for (int r = 0; r < 4; r++)
            pm[r] = fmaxf(fmaxf(sc[0][r], sc[1][r]), fmaxf(sc[2][r], sc[3][r]));
        bool ok = true;
#pragma unroll
        for (int r = 0; r < 4; r++) ok = ok && (pm[r] <= m_i[r] + 8.0f);
        if (!__all(ok)) {
#pragma unroll
            for (int off = 1; off < 16; off <<= 1)
#pragma unroll
                for (int r = 0; r < 4; r++) pm[r] = fmaxf(pm[r], __shfl_xor(pm[r], off));
#pragma unroll
            for (int r = 0; r < 4; r++) {
                float mn = fmaxf(m_i[r], pm[r]);
                float al = __expf(m_i[r] - mn);
                m_i[r] = mn;
                lacc[r] *= al;
#pragma unroll
                for (int t = 0; t < 4; t++) o[t][r] *= al;
            }
        }

        // P = exp(S - m), C layout -> A-operand layout via wave-private LDS
#pragma unroll
        for (int t = 0; t < 4; t++)
#pragma unroll
            for (int r = 0; r < 4; r++)
                Prow[(quad * 4 + r) * 72 + t * 16 + l15] =
                    __float2bfloat16(__expf(sc[t][r] - m_i[r]));

        // O += P V ; l += P @ ones (row-sum via MFMA, no shuffle chain)
#pragma unroll
        for (int st = 0; st < 2; st++) {
            bf16x8 pf = *(const bf16x8*)(&Prow[l15 * 72 + st * 32 + quad * 8]);
            __builtin_amdgcn_s_setprio(1);
            lacc = MFMA16(pf, ones, lacc);
#pragma unroll
            for (int t = 0; t < 4; t++)
                o[t] = MFMA16(pf, vf[st][t], o[t]);
            __builtin_amdgcn_s_setprio(0);
        }

        // rotate K double buffer
#pragma unroll
        for (int st = 0; st < 2; st++)
#pragma unroll
            for (int t = 0; t < 4; t++)
                kf[st][t] = kfn[st][t];
    }

    // ---- diagonal kv tile: causal mask, no prefetch ----
    {
        const int kv0 = qi * 64;

        bf16x8 vf[2][4];
#pragma unroll
        for (int st = 0; st < 2; st++)
#pragma unroll
            for (int t = 0; t < 4; t++)
                vf[st][t] = *(const bf16x8*)(Vtb + (size_t)(t * 16 + l15) * S_LEN + kv0 + st * 32 + quad * 8);

        f32x4 sc[4] = {};
        __builtin_amdgcn_s_setprio(1);
#pragma unroll
        for (int st = 0; st < 2; st++)
#pragma unroll
            for (int t = 0; t < 4; t++)
                sc[t] = MFMA16(qf[st], kf[st][t], sc[t]);
        __builtin_amdgcn_s_setprio(0);

#pragma unroll
        for (int t = 0; t < 4; t++) {
            int col = kv0 + t * 16 + l15;
#pragma unroll
            for (int r = 0; r < 4; r++) {
                int row = q0 + w * 16 + quad * 4 + r;
                if (col > row) sc[t][r] = NEG_BIG;
            }
        }

        float pm[4];
#pragma unroll
        for (int r = 0; r < 4; r++)
            pm[r] = fmaxf(fmaxf(sc[0][r], sc[1][r]), fmaxf(sc[2][r], sc[3][r]));
        bool ok = true;
#pragma unroll
        for (int r = 0; r < 4; r++) ok = ok && (pm[r] <= m_i[r] + 8.0f);
        if (!__all(ok)) {
#pragma unroll
            for (int off = 1; off < 16; off <<= 1)
#pragma unroll
                for (int r = 0; r < 4; r++) pm[r] = fmaxf(pm[r], __shfl_xor(pm[r], off));
#pragma unroll
            for (int r = 0; r < 4; r++) {
                float mn = fmaxf(m_i[r], pm[r]);
                float al = __expf(m_i[r] - mn);
                m_i[r] = mn;
                lacc[r] *= al;
#pragma unroll
                for (int t = 0; t < 4; t++) o[t][r] *= al;
            }
        }

#pragma unroll
        for (int t = 0; t < 4; t++)
#pragma unroll
            for (int r = 0; r < 4; r++)
                Prow[(quad * 4 + r) * 72 + t * 16 + l15] =
                    __float2bfloat16(__expf(sc[t][r] - m_i[r]));

#pragma unroll
        for (int st = 0; st < 2; st++) {
            bf16x8 pf = *(const bf16x8*)(&Prow[l15 * 72 + st * 32 + quad * 8]);
            __builtin_amdgcn_s_setprio(1);
            lacc = MFMA16(pf, ones, lacc);
#pragma unroll
            for (int t = 0; t < 4; t++)
                o[t] = MFMA16(pf, vf[st][t], o[t]);
            __builtin_amdgcn_s_setprio(0);
        }
    }

    // epilogue: O/l -> (B,S,D)
#pragma unroll
    for (int t = 0; t < 4; t++)
#pragma unroll
        for (int r = 0; r < 4; r++) {
            int s = q0 + w * 16 + quad * 4 + r;
            int d = t * 16 + l15;
            float val = o[t][r] / lacc[r];
            Og[((size_t)(b * S_LEN + s)) * DM + h * HD + d] = __float2bfloat16(val);
        }
}

// ---------------------------------------------------------------------------
// Output projection: out = attn @ Wo^T -> d_out as fp32 (bf16-rounded).
// ---------------------------------------------------------------------------
__global__ __launch_bounds__(256) void oproj_kernel(
    const __hip_bfloat16* __restrict__ A,
    const __hip_bfloat16* __restrict__ W,
    float* __restrict__ out)
{
    constexpr int LDK = 40;
    __shared__ __align__(16) __hip_bfloat16 Asm[128 * LDK];
    __shared__ __align__(16) __hip_bfloat16 Bsm[128 * LDK];

    const int tid = threadIdx.x;
    const int wave = tid >> 6, lane = tid & 63;
    const int quad = lane >> 4, l15 = lane & 15;
    const int wm = (wave >> 1) * 64, wn = (wave & 1) * 64;
    const int m0 = blockIdx.y * 128, n0 = blockIdx.x * 128;

    f32x4 acc[4][4] = {};

    for (int k0 = 0; k0 < DM; k0 += 32) {
#pragma unroll
        for (int c = 0; c < 2; c++) {
            int idx = c * 2048 + tid * 8;
            int r = idx >> 5, kc = idx & 31;
            *(int4*)(&Asm[r * LDK + kc]) = *(const int4*)(A + (size_t)(m0 + r) * DM + k0 + kc);
            *(int4*)(&Bsm[r * LDK + kc]) = *(const int4*)(W + (size_t)(n0 + r) * DM + k0 + kc);
        }
        __syncthreads();
        bf16x8 af[4], bfv[4];
#pragma unroll
        for (int i = 0; i < 4; i++)
            af[i] = *(const bf16x8*)(&Asm[(wm + i * 16 + l15) * LDK + quad * 8]);
#pragma unroll
        for (int j = 0; j < 4; j++)
            bfv[j] = *(const bf16x8*)(&Bsm[(wn + j * 16 + l15) * LDK + quad * 8]);
#pragma unroll
        for (int i = 0; i < 4; i++)
#pragma unroll
            for (int j = 0; j < 4; j++)
                acc[i][j] = MFMA16(af[i], bfv[j], acc[i][j]);
        __syncthreads();
    }

#pragma unroll
    for (int i = 0; i < 4; i++)
#pragma unroll
        for (int r = 0; r < 4; r++) {
            int m = m0 + wm + i * 16 + quad * 4 + r;
#pragma unroll
            for (int j = 0; j < 4; j++) {
                int col = n0 + wn + j * 16 + l15;
                __hip_bfloat16 bb = __float2bfloat16(acc[i][j][r]);
                unsigned int u = ((unsigned int)(*(unsigned short*)&bb)) << 16;
                out[(size_t)m * DM + col] = __uint_as_float(u);
            }
        }
}

// ---------------------------------------------------------------------------
extern "C" void kernel_launch(void* const* d_in, const int* in_sizes, int n_in,
                              void* d_out, int out_size, void* d_ws, size_t ws_size,
                              hipStream_t stream)
{
    const float* x  = (const float*)d_in[0];
    const float* wq = (const float*)d_in[1];
    const float* wk = (const float*)d_in[2];
    const float* wv = (const float*)d_in[3];
    const float* wo = (const float*)d_in[4];
    float* out = (float*)d_out;

    const size_t xe = (size_t)2 * S_LEN * DM;
    const size_t we = (size_t)DM * DM;
    __hip_bfloat16* xb  = (__hip_bfloat16*)d_ws;
    __hip_bfloat16* wqb = xb + xe;
    __hip_bfloat16* wkb = wqb + we;
    __hip_bfloat16* wvb = wkb + we;
    __hip_bfloat16* wob = wvb + we;
    __hip_bfloat16* qws = wob + we;
    __hip_bfloat16* kws = qws + xe;
    __hip_bfloat16* vws = kws + xe;   // V^T (B,H,hd,S)
    __hip_bfloat16* aws = vws + xe;

    dim3 blk(256, 1, 1);
    convert_kernel<<<dim3(1024, 8, 1), blk, 0, stream>>>(x, wq, wk, wv, wo,
                                                         xb, wqb, wkb, wvb, wob);
    qkv_kernel<<<dim3(8, 32, 3), blk, 0, stream>>>(xb, wqb, wkb, wvb, qws, kws, vws);
    rope_kernel<<<dim3(2048, 2, 1), blk, 0, stream>>>(qws, kws);
    attn_kernel<<<dim3(16, 64, 1), blk, 0, stream>>>(qws, kws, vws, aws);
    oproj_kernel<<<dim3(8, 32, 1), blk, 0, stream>>>(aws, wob, out);
}

// Round 3
// 237.664 us; speedup vs baseline: 1.6755x; 1.2761x over previous
//
#include <hip/hip_runtime.h>
#include <hip/hip_bf16.h>
#include <math.h>

// Multi-head self-attention w/ RoPE, causal. B=2, S=2048, H=16, hd=64, D=1024.
// fp32 inputs -> bf16 ws -> qkv GEMMs (V stored transposed) -> RoPE (Q pre-scaled
// by 1/8) -> barrier-free dual-chain flash attention -> oproj -> fp32 output.
// attn: BW-bound on K/V re-fetch (r0-r2 counters: dur == hbm_bytes/hbm_bw).
// Fix: 128-row super-tiles (each wave runs TWO 16-row chains sharing every K/V
// fragment load -> halves fetch demand) + head-pinned-to-XCD grid (bx=head,
// n&7=bx&7 -> 4 heads x 512KB = 2MB K/V per XCD L2) + per-CU anti-paired qi.
// ws: xb(8MB) wq/wk/wv/wo(2MB ea) q,k,vT(8MB ea) attn_out(8MB) = 48MB.

#define S_LEN 2048
#define NHEADS 16
#define HD 64
#define DM 1024

typedef __attribute__((ext_vector_type(8))) short bf16x8;  // MFMA A/B frag (4 VGPRs)
typedef __attribute__((ext_vector_type(4))) float f32x4;   // MFMA C/D frag

#define MFMA16(a, b, c) __builtin_amdgcn_mfma_f32_16x16x32_bf16((a), (b), (c), 0, 0, 0)
#define NEG_BIG (-1e30f)  // finite mask sentinel

// ---------------------------------------------------------------------------
// fp32 -> bf16 conversion pre-pass.
// ---------------------------------------------------------------------------
__global__ __launch_bounds__(256) void convert_kernel(
    const float* __restrict__ x,  const float* __restrict__ wq,
    const float* __restrict__ wk, const float* __restrict__ wv,
    const float* __restrict__ wo,
    __hip_bfloat16* __restrict__ xb,  __hip_bfloat16* __restrict__ wqb,
    __hip_bfloat16* __restrict__ wkb, __hip_bfloat16* __restrict__ wvb,
    __hip_bfloat16* __restrict__ wob)
{
    const int y = blockIdx.y;
    const float* src;
    __hip_bfloat16* dst;
    size_t off = 0;
    if (y < 4)      { src = x;  dst = xb;  off = (size_t)y * 1048576; }
    else if (y == 4) { src = wq; dst = wqb; }
    else if (y == 5) { src = wk; dst = wkb; }
    else if (y == 6) { src = wv; dst = wvb; }
    else             { src = wo; dst = wob; }

    const size_t i = off + ((size_t)blockIdx.x * 256 + threadIdx.x) * 4;
    float4 v = *(const float4*)(src + i);
    __hip_bfloat16 t[4] = { __float2bfloat16(v.x), __float2bfloat16(v.y),
                            __float2bfloat16(v.z), __float2bfloat16(v.w) };
    *(ushort4*)(dst + i) = *(ushort4*)t;
}

// ---------------------------------------------------------------------------
// GEMM: C[m,n] = sum_k A[m,k] * W[n,k]. 128x128 tile, BK=32, 4 waves 2x2.
// z=0,1 (Q,K): out (B,H,S,hd).  z=2 (V): out TRANSPOSED (B,H,hd,S) so the
// attention PV B-operand loads contiguously from global.
// ---------------------------------------------------------------------------
__global__ __launch_bounds__(256) void qkv_kernel(
    const __hip_bfloat16* __restrict__ X,
    const __hip_bfloat16* __restrict__ Wq,
    const __hip_bfloat16* __restrict__ Wk,
    const __hip_bfloat16* __restrict__ Wv,
    __hip_bfloat16* __restrict__ qws,
    __hip_bfloat16* __restrict__ kws,
    __hip_bfloat16* __restrict__ vws)
{
    const int z = blockIdx.z;
    const __hip_bfloat16* __restrict__ W = (z == 0) ? Wq : (z == 1) ? Wk : Wv;
    __hip_bfloat16* __restrict__ out = (z == 0) ? qws : (z == 1) ? kws : vws;

    constexpr int LDK = 40;
    __shared__ __align__(16) __hip_bfloat16 Asm[128 * LDK];
    __shared__ __align__(16) __hip_bfloat16 Bsm[128 * LDK];

    const int tid = threadIdx.x;
    const int wave = tid >> 6, lane = tid & 63;
    const int quad = lane >> 4, l15 = lane & 15;
    const int wm = (wave >> 1) * 64, wn = (wave & 1) * 64;
    const int m0 = blockIdx.y * 128, n0 = blockIdx.x * 128;

    f32x4 acc[4][4] = {};

    for (int k0 = 0; k0 < DM; k0 += 32) {
#pragma unroll
        for (int c = 0; c < 2; c++) {
            int idx = c * 2048 + tid * 8;
            int r = idx >> 5, kc = idx & 31;
            *(int4*)(&Asm[r * LDK + kc]) = *(const int4*)(X + (size_t)(m0 + r) * DM + k0 + kc);
            *(int4*)(&Bsm[r * LDK + kc]) = *(const int4*)(W + (size_t)(n0 + r) * DM + k0 + kc);
        }
        __syncthreads();
        bf16x8 af[4], bfv[4];
#pragma unroll
        for (int i = 0; i < 4; i++)
            af[i] = *(const bf16x8*)(&Asm[(wm + i * 16 + l15) * LDK + quad * 8]);
#pragma unroll
        for (int j = 0; j < 4; j++)
            bfv[j] = *(const bf16x8*)(&Bsm[(wn + j * 16 + l15) * LDK + quad * 8]);
#pragma unroll
        for (int i = 0; i < 4; i++)
#pragma unroll
            for (int j = 0; j < 4; j++)
                acc[i][j] = MFMA16(af[i], bfv[j], acc[i][j]);
        __syncthreads();
    }

#pragma unroll
    for (int i = 0; i < 4; i++) {
#pragma unroll
        for (int r = 0; r < 4; r++) {
            int m = m0 + wm + i * 16 + quad * 4 + r;
            int b = m >> 11, s = m & 2047;
#pragma unroll
            for (int j = 0; j < 4; j++) {
                int col = n0 + wn + j * 16 + l15;
                int h = col >> 6, d = col & 63;
                size_t idx = (z == 2)
                    ? (((size_t)(b * NHEADS + h)) * HD + d) * S_LEN + s    // V^T: (B,H,hd,S)
                    : (((size_t)(b * NHEADS + h)) * S_LEN + s) * HD + d;   // Q,K: (B,H,S,hd)
                out[idx] = __float2bfloat16(acc[i][j][r]);
            }
        }
    }
}

// ---------------------------------------------------------------------------
// RoPE in-place on q,k laid out (B,H,S,hd). Q additionally pre-scaled by
// 1/sqrt(hd)=0.125 (exact in bf16: power of 2) so attn skips per-score scaling.
// ---------------------------------------------------------------------------
__global__ __launch_bounds__(256) void rope_kernel(
    __hip_bfloat16* __restrict__ q, __hip_bfloat16* __restrict__ k)
{
    __hip_bfloat16* __restrict__ p = (blockIdx.y == 0) ? q : k;
    const float qscale = (blockIdx.y == 0) ? 0.125f : 1.0f;
    const int gid = blockIdx.x * 256 + threadIdx.x;       // [0, 524288)
    const int e0 = gid * 8;
    const int s = (gid >> 3) & 2047;
    const int d0 = (gid & 7) * 8;

    int4 raw = *(const int4*)(p + e0);
    __hip_bfloat16* v = (__hip_bfloat16*)&raw;
#pragma unroll
    for (int i = 0; i < 4; i++) {
        int pi = (d0 >> 1) + i;
        float theta = powf(10000.0f, -(float)(2 * pi) * (1.0f / 64.0f));
        float sn, cs;
        sincosf((float)s * theta, &sn, &cs);
        float x1 = __bfloat162float(v[2 * i]);
        float x2 = __bfloat162float(v[2 * i + 1]);
        v[2 * i]     = __float2bfloat16((x1 * cs - x2 * sn) * qscale);
        v[2 * i + 1] = __float2bfloat16((x1 * sn + x2 * cs) * qscale);
    }
    *(int4*)(p + e0) = raw;
}

// ---------------------------------------------------------------------------
// Dual-chain flash attention. Block = 4 independent waves. Each wave runs TWO
// 16-row chains (rows q0+w*16 and q0+64+w*16 of a 128-row super-tile), sharing
// every K/V fragment load between the chains -> K/V fetch demand halves and
// per-wave ILP doubles. Grid (32,16): bx = head (block id n = bx+32*by ->
// n&7 = bx&7 pins the 16 q-blocks of a head to one XCD: 4 heads x 512KB K/V
// = 2MB per 4MB XCD L2). qi = by<8 ? by : 23-by anti-pairs per CU (n, n+256
// -> qi b0 & 15-b0: equal per-CU totals). kv-tiles: j<2qi full (no mask),
// j=2qi chain-A diagonal + B full, j=2qi+1 B diagonal only. K single-buffered:
// refill issued right after QK^T, consumed next iter (softmax+PV covers the
// latency). Defer-max softmax (THR=8), l via ones-MFMA, wave-private LDS for
// the P C->A layout transform, s_setprio(1) around MFMA clusters.
// ---------------------------------------------------------------------------

// per-16-row-tile online softmax + PV (uses quad,l15,ones,vf from scope)
#define SMPV(sc, mm, ll, oo, Pr)                                               \
    do {                                                                       \
        float pm[4];                                                           \
        _Pragma("unroll")                                                      \
        for (int r = 0; r < 4; r++)                                            \
            pm[r] = fmaxf(fmaxf(sc[0][r], sc[1][r]),                           \
                          fmaxf(sc[2][r], sc[3][r]));                          \
        bool ok = true;                                                        \
        _Pragma("unroll")                                                      \
        for (int r = 0; r < 4; r++) ok = ok && (pm[r] <= mm[r] + 8.0f);        \
        if (!__all(ok)) {                                                      \
            _Pragma("unroll")                                                  \
            for (int off = 1; off < 16; off <<= 1)                             \
                _Pragma("unroll")                                              \
                for (int r = 0; r < 4; r++)                                    \
                    pm[r] = fmaxf(pm[r], __shfl_xor(pm[r], off));              \
            _Pragma("unroll")                                                  \
            for (int r = 0; r < 4; r++) {                                      \
                float mn = fmaxf(mm[r], pm[r]);                                \
                float al = __expf(mm[r] - mn);                                 \
                mm[r] = mn;                                                    \
                ll[r] *= al;                                                   \
                _Pragma("unroll")                                              \
                for (int t = 0; t < 4; t++) oo[t][r] *= al;                    \
            }                                                                  \
        }                                                                      \
        _Pragma("unroll")                                                      \
        for (int t = 0; t < 4; t++)                                            \
            _Pragma("unroll")                                                  \
            for (int r = 0; r < 4; r++)                                        \
                Pr[(quad * 4 + r) * 72 + t * 16 + l15] =                       \
                    __float2bfloat16(__expf(sc[t][r] - mm[r]));                \
        _Pragma("unroll")                                                      \
        for (int st = 0; st < 2; st++) {                                       \
            bf16x8 pf = *(const bf16x8*)(&Pr[l15 * 72 + st * 32 + quad * 8]);  \
            __builtin_amdgcn_s_setprio(1);                                     \
            ll = MFMA16(pf, ones, ll);                                         \
            _Pragma("unroll")                                                  \
            for (int t = 0; t < 4; t++) oo[t] = MFMA16(pf, vf[st][t], oo[t]);  \
            __builtin_amdgcn_s_setprio(0);                                     \
        }                                                                      \
    } while (0)

#define LOAD_VF(kv0)                                                           \
    do {                                                                       \
        _Pragma("unroll")                                                      \
        for (int st = 0; st < 2; st++)                                         \
            _Pragma("unroll")                                                  \
            for (int t = 0; t < 4; t++)                                        \
                vf[st][t] = *(const bf16x8*)(Vtb +                             \
                    (size_t)(t * 16 + l15) * S_LEN + (kv0) + st * 32 + quad * 8); \
    } while (0)

#define LOAD_KF(kv0)                                                           \
    do {                                                                       \
        _Pragma("unroll")                                                      \
        for (int st = 0; st < 2; st++)                                         \
            _Pragma("unroll")                                                  \
            for (int t = 0; t < 4; t++)                                        \
                kf[st][t] = *(const bf16x8*)(Kb +                              \
                    (size_t)((kv0) + t * 16 + l15) * HD + st * 32 + quad * 8); \
    } while (0)

#define QK(sc, qf)                                                             \
    do {                                                                       \
        __builtin_amdgcn_s_setprio(1);                                         \
        _Pragma("unroll")                                                      \
        for (int st = 0; st < 2; st++)                                         \
            _Pragma("unroll")                                                  \
            for (int t = 0; t < 4; t++) sc[t] = MFMA16(qf[st], kf[st][t], sc[t]); \
        __builtin_amdgcn_s_setprio(0);                                         \
    } while (0)

#define MASK(sc, rowbase, kv0)                                                 \
    do {                                                                       \
        _Pragma("unroll")                                                      \
        for (int t = 0; t < 4; t++) {                                          \
            int col = (kv0) + t * 16 + l15;                                    \
            _Pragma("unroll")                                                  \
            for (int r = 0; r < 4; r++) {                                      \
                int row = (rowbase) + quad * 4 + r;                            \
                if (col > row) sc[t][r] = NEG_BIG;                             \
            }                                                                  \
        }                                                                      \
    } while (0)

__global__ __launch_bounds__(256) void attn_kernel(
    const __hip_bfloat16* __restrict__ Qg,
    const __hip_bfloat16* __restrict__ Kg,
    const __hip_bfloat16* __restrict__ Vtg,  // (B,H,hd,S)
    __hip_bfloat16* __restrict__ Og)         // (B,S,D)
{
    const int bh = blockIdx.x;                               // head -> XCD pin
    const int qi = (blockIdx.y < 8) ? blockIdx.y : 23 - blockIdx.y;
    const int tid = threadIdx.x;
    const int w = tid >> 6, lane = tid & 63;
    const int quad = lane >> 4, l15 = lane & 15;
    const size_t base = (size_t)bh * S_LEN * HD;
    const __hip_bfloat16* Qb = Qg + base;
    const __hip_bfloat16* Kb = Kg + base;
    const __hip_bfloat16* Vtb = Vtg + base;
    const int b = bh >> 4, h = bh & 15;

    __shared__ __align__(16) __hip_bfloat16 Pl[128 * 72];
    __hip_bfloat16* PrA = &Pl[w * 32 * 72];   // wave-private 16x64(+8 pad)
    __hip_bfloat16* PrB = PrA + 16 * 72;

    const int q0 = qi * 128;
    const int rowA = q0 + w * 16;             // chain A rows rowA..rowA+15
    const int rowB = rowA + 64;               // chain B rows

    bf16x8 qfA[2], qfB[2];
#pragma unroll
    for (int st = 0; st < 2; st++) {
        qfA[st] = *(const bf16x8*)(Qb + (size_t)(rowA + l15) * HD + st * 32 + quad * 8);
        qfB[st] = *(const bf16x8*)(Qb + (size_t)(rowB + l15) * HD + st * 32 + quad * 8);
    }

    bf16x8 ones;
#pragma unroll
    for (int i = 0; i < 8; i++) ones[i] = (short)0x3F80;  // bf16 1.0

    float mA[4], mB[4];
    f32x4 lA = {}, lB = {};
    f32x4 oA[4] = {}, oB[4] = {};
#pragma unroll
    for (int r = 0; r < 4; r++) { mA[r] = NEG_BIG; mB[r] = NEG_BIG; }

    bf16x8 kf[2][4];
    bf16x8 vf[2][4];
    LOAD_KF(0);  // prime K tile j=0

    // ---- full dual tiles: j = 0 .. 2qi-1, no masking ----
#pragma unroll 1
    for (int j = 0; j < 2 * qi; j++) {
        const int kv0 = j * 64;
        LOAD_VF(kv0);
        f32x4 scA[4] = {}, scB[4] = {};
        QK(scA, qfA);
        QK(scB, qfB);
        LOAD_KF(kv0 + 64);  // single-buffer refill; consumed next iter
        SMPV(scA, mA, lA, oA, PrA);
        SMPV(scB, mB, lB, oB, PrB);
    }

    // ---- j = 2qi: chain A diagonal, chain B full ----
    {
        const int kv0 = q0;
        LOAD_VF(kv0);
        f32x4 scA[4] = {}, scB[4] = {};
        QK(scA, qfA);
        QK(scB, qfB);
        LOAD_KF(kv0 + 64);
        MASK(scA, rowA, kv0);
        SMPV(scA, mA, lA, oA, PrA);
        SMPV(scB, mB, lB, oB, PrB);
    }

    // ---- j = 2qi+1: chain B diagonal only ----
    {
        const int kv0 = q0 + 64;
        LOAD_VF(kv0);
        f32x4 scB[4] = {};
        QK(scB, qfB);
        MASK(scB, rowB, kv0);
        SMPV(scB, mB, lB, oB, PrB);
    }

    // epilogue: O/l -> (B,S,D), both chains
#pragma unroll
    for (int t = 0; t < 4; t++)
#pragma unroll
        for (int r = 0; r < 4; r++) {
            int d = t * 16 + l15;
            int sA = rowA + quad * 4 + r;
            Og[((size_t)(b * S_LEN + sA)) * DM + h * HD + d] =
                __float2bfloat16(oA[t][r] / lA[r]);
            int sB = rowB + quad * 4 + r;
            Og[((size_t)(b * S_LEN + sB)) * DM + h * HD + d] =
                __float2bfloat16(oB[t][r] / lB[r]);
        }
}

// ---------------------------------------------------------------------------
// Output projection: out = attn @ Wo^T -> d_out as fp32 (bf16-rounded).
// ---------------------------------------------------------------------------
__global__ __launch_bounds__(256) void oproj_kernel(
    const __hip_bfloat16* __restrict__ A,
    const __hip_bfloat16* __restrict__ W,
    float* __restrict__ out)
{
    constexpr int LDK = 40;
    __shared__ __align__(16) __hip_bfloat16 Asm[128 * LDK];
    __shared__ __align__(16) __hip_bfloat16 Bsm[128 * LDK];

    const int tid = threadIdx.x;
    const int wave = tid >> 6, lane = tid & 63;
    const int quad = lane >> 4, l15 = lane & 15;
    const int wm = (wave >> 1) * 64, wn = (wave & 1) * 64;
    const int m0 = blockIdx.y * 128, n0 = blockIdx.x * 128;

    f32x4 acc[4][4] = {};

    for (int k0 = 0; k0 < DM; k0 += 32) {
#pragma unroll
        for (int c = 0; c < 2; c++) {
            int idx = c * 2048 + tid * 8;
            int r = idx >> 5, kc = idx & 31;
            *(int4*)(&Asm[r * LDK + kc]) = *(const int4*)(A + (size_t)(m0 + r) * DM + k0 + kc);
            *(int4*)(&Bsm[r * LDK + kc]) = *(const int4*)(W + (size_t)(n0 + r) * DM + k0 + kc);
        }
        __syncthreads();
        bf16x8 af[4], bfv[4];
#pragma unroll
        for (int i = 0; i < 4; i++)
            af[i] = *(const bf16x8*)(&Asm[(wm + i * 16 + l15) * LDK + quad * 8]);
#pragma unroll
        for (int j = 0; j < 4; j++)
            bfv[j] = *(const bf16x8*)(&Bsm[(wn + j * 16 + l15) * LDK + quad * 8]);
#pragma unroll
        for (int i = 0; i < 4; i++)
#pragma unroll
            for (int j = 0; j < 4; j++)
                acc[i][j] = MFMA16(af[i], bfv[j], acc[i][j]);
        __syncthreads();
    }

#pragma unroll
    for (int i = 0; i < 4; i++)
#pragma unroll
        for (int r = 0; r < 4; r++) {
            int m = m0 + wm + i * 16 + quad * 4 + r;
#pragma unroll
            for (int j = 0; j < 4; j++) {
                int col = n0 + wn + j * 16 + l15;
                __hip_bfloat16 bb = __float2bfloat16(acc[i][j][r]);
                unsigned int u = ((unsigned int)(*(unsigned short*)&bb)) << 16;
                out[(size_t)m * DM + col] = __uint_as_float(u);
            }
        }
}

// ---------------------------------------------------------------------------
extern "C" void kernel_launch(void* const* d_in, const int* in_sizes, int n_in,
                              void* d_out, int out_size, void* d_ws, size_t ws_size,
                              hipStream_t stream)
{
    const float* x  = (const float*)d_in[0];
    const float* wq = (const float*)d_in[1];
    const float* wk = (const float*)d_in[2];
    const float* wv = (const float*)d_in[3];
    const float* wo = (const float*)d_in[4];
    float* out = (float*)d_out;

    const size_t xe = (size_t)2 * S_LEN * DM;
    const size_t we = (size_t)DM * DM;
    __hip_bfloat16* xb  = (__hip_bfloat16*)d_ws;
    __hip_bfloat16* wqb = xb + xe;
    __hip_bfloat16* wkb = wqb + we;
    __hip_bfloat16* wvb = wkb + we;
    __hip_bfloat16* wob = wvb + we;
    __hip_bfloat16* qws = wob + we;
    __hip_bfloat16* kws = qws + xe;
    __hip_bfloat16* vws = kws + xe;   // V^T (B,H,hd,S)
    __hip_bfloat16* aws = vws + xe;

    dim3 blk(256, 1, 1);
    convert_kernel<<<dim3(1024, 8, 1), blk, 0, stream>>>(x, wq, wk, wv, wo,
                                                         xb, wqb, wkb, wvb, wob);
    qkv_kernel<<<dim3(8, 32, 3), blk, 0, stream>>>(xb, wqb, wkb, wvb, qws, kws, vws);
    rope_kernel<<<dim3(2048, 2, 1), blk, 0, stream>>>(qws, kws);
    attn_kernel<<<dim3(32, 16, 1), blk, 0, stream>>>(qws, kws, vws, aws);
    oproj_kernel<<<dim3(8, 32, 1), blk, 0, stream>>>(aws, wob, out);
}

// Round 4
// 216.169 us; speedup vs baseline: 1.8421x; 1.0994x over previous
//
#include <hip/hip_runtime.h>
#include <hip/hip_bf16.h>
#include <math.h>

// Multi-head self-attention w/ RoPE, causal. B=2, S=2048, H=16, hd=64, D=1024.
// fp32 inputs -> bf16 ws (+ RoPE cos/sin table) -> qkv GEMMs via global_load_lds
// (V stored transposed) -> table-driven RoPE (Q pre-scaled by 0.125*log2e) ->
// barrier-free dual-chain flash attention (exp2-domain softmax) -> oproj.
// attn fetch fixed in r3: 128-row super-tiles (wave runs TWO 16-row chains
// sharing K/V frag loads) + head-pinned-to-XCD grid -> FETCH 101->12 MB.
// ws: xb(8MB) wq/wk/wv/wo(2MB ea) q,k,vT(8MB ea) attn_out(8MB) = 48MB.
// RoPE table (512KB) lives at the head of the attn_out region (aws written
// only later, by attn).

#define S_LEN 2048
#define NHEADS 16
#define HD 64
#define DM 1024

typedef __attribute__((ext_vector_type(8))) short bf16x8;  // MFMA A/B frag (4 VGPRs)
typedef __attribute__((ext_vector_type(4))) float f32x4;   // MFMA C/D frag

#define MFMA16(a, b, c) __builtin_amdgcn_mfma_f32_16x16x32_bf16((a), (b), (c), 0, 0, 0)
#define NEG_BIG (-1e30f)  // finite mask sentinel

// async global->LDS, 16B per lane. LDS dest must be linear in lane order.
#define GLOAD_LDS16(g, l)                                                      \
    __builtin_amdgcn_global_load_lds(                                          \
        (const __attribute__((address_space(1))) void*)(g),                    \
        (__attribute__((address_space(3))) void*)(l), 16, 0, 0)

// ---------------------------------------------------------------------------
// fp32 -> bf16 conversion pre-pass + RoPE cos/sin table (plane y==8).
// ---------------------------------------------------------------------------
__global__ __launch_bounds__(256) void convert_kernel(
    const float* __restrict__ x,  const float* __restrict__ wq,
    const float* __restrict__ wk, const float* __restrict__ wv,
    const float* __restrict__ wo,
    __hip_bfloat16* __restrict__ xb,  __hip_bfloat16* __restrict__ wqb,
    __hip_bfloat16* __restrict__ wkb, __hip_bfloat16* __restrict__ wvb,
    __hip_bfloat16* __restrict__ wob, float2* __restrict__ tab)
{
    const int y = blockIdx.y;
    if (y == 8) {  // RoPE table: tab[s*32+p] = (cos, sin) of s*theta_p
        const int gid = blockIdx.x * 256 + threadIdx.x;
        if (gid < S_LEN * 32) {
            const int s = gid >> 5, p = gid & 31;
            float theta = powf(10000.0f, -(float)(2 * p) * (1.0f / 64.0f));
            float sn, cs;
            sincosf((float)s * theta, &sn, &cs);
            tab[gid] = make_float2(cs, sn);
        }
        return;
    }
    const float* src;
    __hip_bfloat16* dst;
    size_t off = 0;
    if (y < 4)      { src = x;  dst = xb;  off = (size_t)y * 1048576; }
    else if (y == 4) { src = wq; dst = wqb; }
    else if (y == 5) { src = wk; dst = wkb; }
    else if (y == 6) { src = wv; dst = wvb; }
    else             { src = wo; dst = wob; }

    const size_t i = off + ((size_t)blockIdx.x * 256 + threadIdx.x) * 4;
    float4 v = *(const float4*)(src + i);
    __hip_bfloat16 t[4] = { __float2bfloat16(v.x), __float2bfloat16(v.y),
                            __float2bfloat16(v.z), __float2bfloat16(v.w) };
    *(ushort4*)(dst + i) = *(ushort4*)t;
}

// ---------------------------------------------------------------------------
// GEMM: C[m,n] = sum_k A[m,k] * W[n,k]. 128x128 tile, BK=32, 4 waves 2x2.
// Staging via global_load_lds width=16 (linear LDS, no pad -- intrinsic
// requires contiguous lane-order dest; m151: +35% vs reg-staging at 128^2).
// z=0,1 (Q,K): out (B,H,S,hd).  z=2 (V): out TRANSPOSED (B,H,hd,S).
// ---------------------------------------------------------------------------
__global__ __launch_bounds__(256) void qkv_kernel(
    const __hip_bfloat16* __restrict__ X,
    const __hip_bfloat16* __restrict__ Wq,
    const __hip_bfloat16* __restrict__ Wk,
    const __hip_bfloat16* __restrict__ Wv,
    __hip_bfloat16* __restrict__ qws,
    __hip_bfloat16* __restrict__ kws,
    __hip_bfloat16* __restrict__ vws)
{
    const int z = blockIdx.z;
    const __hip_bfloat16* __restrict__ W = (z == 0) ? Wq : (z == 1) ? Wk : Wv;
    __hip_bfloat16* __restrict__ out = (z == 0) ? qws : (z == 1) ? kws : vws;

    __shared__ __align__(16) __hip_bfloat16 Asm[128 * 32];
    __shared__ __align__(16) __hip_bfloat16 Bsm[128 * 32];

    const int tid = threadIdx.x;
    const int wave = tid >> 6, lane = tid & 63;
    const int quad = lane >> 4, l15 = lane & 15;
    const int wm = (wave >> 1) * 64, wn = (wave & 1) * 64;
    const int m0 = blockIdx.y * 128, n0 = blockIdx.x * 128;

    f32x4 acc[4][4] = {};

    for (int k0 = 0; k0 < DM; k0 += 32) {
#pragma unroll
        for (int c = 0; c < 2; c++) {
            int idx = c * 2048 + tid * 8;           // element idx, 16B/lane
            int r = idx >> 5, kc = idx & 31;
            GLOAD_LDS16(X + (size_t)(m0 + r) * DM + k0 + kc, &Asm[idx]);
            GLOAD_LDS16(W + (size_t)(n0 + r) * DM + k0 + kc, &Bsm[idx]);
        }
        __syncthreads();   // compiler emits vmcnt(0) drain before barrier
        bf16x8 af[4], bfv[4];
#pragma unroll
        for (int i = 0; i < 4; i++)
            af[i] = *(const bf16x8*)(&Asm[(wm + i * 16 + l15) * 32 + quad * 8]);
#pragma unroll
        for (int j = 0; j < 4; j++)
            bfv[j] = *(const bf16x8*)(&Bsm[(wn + j * 16 + l15) * 32 + quad * 8]);
#pragma unroll
        for (int i = 0; i < 4; i++)
#pragma unroll
            for (int j = 0; j < 4; j++)
                acc[i][j] = MFMA16(af[i], bfv[j], acc[i][j]);
        __syncthreads();
    }

#pragma unroll
    for (int i = 0; i < 4; i++) {
#pragma unroll
        for (int r = 0; r < 4; r++) {
            int m = m0 + wm + i * 16 + quad * 4 + r;
            int b = m >> 11, s = m & 2047;
#pragma unroll
            for (int j = 0; j < 4; j++) {
                int col = n0 + wn + j * 16 + l15;
                int h = col >> 6, d = col & 63;
                size_t idx = (z == 2)
                    ? (((size_t)(b * NHEADS + h)) * HD + d) * S_LEN + s    // V^T: (B,H,hd,S)
                    : (((size_t)(b * NHEADS + h)) * S_LEN + s) * HD + d;   // Q,K: (B,H,S,hd)
                out[idx] = __float2bfloat16(acc[i][j][r]);
            }
        }
    }
}

// ---------------------------------------------------------------------------
// RoPE in-place on q,k laid out (B,H,S,hd), table-driven (no trig in hot
// path). Q additionally pre-scaled by 0.125*log2(e) so the attn softmax runs
// in the exp2 domain with no per-score scaling (still exactly one bf16
// rounding per element -> same error profile as the 0.125 version).
// ---------------------------------------------------------------------------
__global__ __launch_bounds__(256) void rope_kernel(
    __hip_bfloat16* __restrict__ q, __hip_bfloat16* __restrict__ k,
    const float2* __restrict__ tab)
{
    __hip_bfloat16* __restrict__ p = (blockIdx.y == 0) ? q : k;
    const float qscale = (blockIdx.y == 0) ? 0.18033688011112042f  // 0.125*log2e
                                           : 1.0f;
    const int gid = blockIdx.x * 256 + threadIdx.x;       // [0, 524288)
    const int e0 = gid * 8;
    const int s = (gid >> 3) & 2047;
    const int p4 = (gid & 7) * 4;                         // first pair index

    const float2* tp = tab + s * 32 + p4;                 // 4 float2, 32B aligned
    float4 t01 = *(const float4*)(tp);                    // cs0,sn0,cs1,sn1
    float4 t23 = *(const float4*)(tp + 2);                // cs2,sn2,cs3,sn3
    float cs[4] = { t01.x, t01.z, t23.x, t23.z };
    float sn[4] = { t01.y, t01.w, t23.y, t23.w };

    int4 raw = *(const int4*)(p + e0);
    __hip_bfloat16* v = (__hip_bfloat16*)&raw;
#pragma unroll
    for (int i = 0; i < 4; i++) {
        float x1 = __bfloat162float(v[2 * i]);
        float x2 = __bfloat162float(v[2 * i + 1]);
        v[2 * i]     = __float2bfloat16((x1 * cs[i] - x2 * sn[i]) * qscale);
        v[2 * i + 1] = __float2bfloat16((x1 * sn[i] + x2 * cs[i]) * qscale);
    }
    *(int4*)(p + e0) = raw;
}

// ---------------------------------------------------------------------------
// Dual-chain flash attention. Block = 4 independent waves. Each wave runs TWO
// 16-row chains (rows q0+w*16 and q0+64+w*16 of a 128-row super-tile), sharing
// every K/V fragment load between the chains -> K/V fetch demand halves and
// per-wave ILP doubles. Grid (32,16): bx = head (block id n = bx+32*by ->
// n&7 = bx&7 pins the 16 q-blocks of a head to one XCD: 4 heads x 512KB K/V
// = 2MB per 4MB XCD L2; r3 measured FETCH 101->12.4 MB). qi = by<8 ? by :
// 23-by anti-pairs per CU. kv-tiles: j<2qi full (no mask), j=2qi chain-A
// diagonal + B full, j=2qi+1 B diagonal only. K single-buffered: refill
// issued right after QK^T, consumed next iter. Softmax in exp2 domain
// (Q carries the 0.125*log2e scale): defer-max THR=11 (~e^8), l via
// ones-MFMA, wave-private LDS for the P C->A transform, s_setprio around
// MFMA clusters.
// ---------------------------------------------------------------------------

// per-16-row-tile online softmax + PV (uses quad,l15,ones,vf from scope)
#define SMPV(sc, mm, ll, oo, Pr)                                               \
    do {                                                                       \
        float pm[4];                                                           \
        _Pragma("unroll")                                                      \
        for (int r = 0; r < 4; r++)                                            \
            pm[r] = fmaxf(fmaxf(sc[0][r], sc[1][r]),                           \
                          fmaxf(sc[2][r], sc[3][r]));                          \
        bool ok = true;                                                        \
        _Pragma("unroll")                                                      \
        for (int r = 0; r < 4; r++) ok = ok && (pm[r] <= mm[r] + 11.0f);       \
        if (!__all(ok)) {                                                      \
            _Pragma("unroll")                                                  \
            for (int off = 1; off < 16; off <<= 1)                             \
                _Pragma("unroll")                                              \
                for (int r = 0; r < 4; r++)                                    \
                    pm[r] = fmaxf(pm[r], __shfl_xor(pm[r], off));              \
            _Pragma("unroll")                                                  \
            for (int r = 0; r < 4; r++) {                                      \
                float mn = fmaxf(mm[r], pm[r]);                                \
                float al = exp2f(mm[r] - mn);                                  \
                mm[r] = mn;                                                    \
                ll[r] *= al;                                                   \
                _Pragma("unroll")                                              \
                for (int t = 0; t < 4; t++) oo[t][r] *= al;                    \
            }                                                                  \
        }                                                                      \
        _Pragma("unroll")                                                      \
        for (int t = 0; t < 4; t++)                                            \
            _Pragma("unroll")                                                  \
            for (int r = 0; r < 4; r++)                                        \
                Pr[(quad * 4 + r) * 72 + t * 16 + l15] =                       \
                    __float2bfloat16(exp2f(sc[t][r] - mm[r]));                 \
        _Pragma("unroll")                                                      \
        for (int st = 0; st < 2; st++) {                                       \
            bf16x8 pf = *(const bf16x8*)(&Pr[l15 * 72 + st * 32 + quad * 8]);  \
            __builtin_amdgcn_s_setprio(1);                                     \
            ll = MFMA16(pf, ones, ll);                                         \
            _Pragma("unroll")                                                  \
            for (int t = 0; t < 4; t++) oo[t] = MFMA16(pf, vf[st][t], oo[t]);  \
            __builtin_amdgcn_s_setprio(0);                                     \
        }                                                                      \
    } while (0)

#define LOAD_VF(kv0)                                                           \
    do {                                                                       \
        _Pragma("unroll")                                                      \
        for (int st = 0; st < 2; st++)                                         \
            _Pragma("unroll")                                                  \
            for (int t = 0; t < 4; t++)                                        \
                vf[st][t] = *(const bf16x8*)(Vtb +                             \
                    (size_t)(t * 16 + l15) * S_LEN + (kv0) + st * 32 + quad * 8); \
    } while (0)

#define LOAD_KF(kv0)                                                           \
    do {                                                                       \
        _Pragma("unroll")                                                      \
        for (int st = 0; st < 2; st++)                                         \
            _Pragma("unroll")                                                  \
            for (int t = 0; t < 4; t++)                                        \
                kf[st][t] = *(const bf16x8*)(Kb +                              \
                    (size_t)((kv0) + t * 16 + l15) * HD + st * 32 + quad * 8); \
    } while (0)

#define QK(sc, qf)                                                             \
    do {                                                                       \
        __builtin_amdgcn_s_setprio(1);                                         \
        _Pragma("unroll")                                                      \
        for (int st = 0; st < 2; st++)                                         \
            _Pragma("unroll")                                                  \
            for (int t = 0; t < 4; t++) sc[t] = MFMA16(qf[st], kf[st][t], sc[t]); \
        __builtin_amdgcn_s_setprio(0);                                         \
    } while (0)

#define MASK(sc, rowbase, kv0)                                                 \
    do {                                                                       \
        _Pragma("unroll")                                                      \
        for (int t = 0; t < 4; t++) {                                          \
            int col = (kv0) + t * 16 + l15;                                    \
            _Pragma("unroll")                                                  \
            for (int r = 0; r < 4; r++) {                                      \
                int row = (rowbase) + quad * 4 + r;                            \
                if (col > row) sc[t][r] = NEG_BIG;                             \
            }                                                                  \
        }                                                                      \
    } while (0)

__global__ __launch_bounds__(256) void attn_kernel(
    const __hip_bfloat16* __restrict__ Qg,
    const __hip_bfloat16* __restrict__ Kg,
    const __hip_bfloat16* __restrict__ Vtg,  // (B,H,hd,S)
    __hip_bfloat16* __restrict__ Og)         // (B,S,D)
{
    const int bh = blockIdx.x;                               // head -> XCD pin
    const int qi = (blockIdx.y < 8) ? blockIdx.y : 23 - blockIdx.y;
    const int tid = threadIdx.x;
    const int w = tid >> 6, lane = tid & 63;
    const int quad = lane >> 4, l15 = lane & 15;
    const size_t base = (size_t)bh * S_LEN * HD;
    const __hip_bfloat16* Qb = Qg + base;
    const __hip_bfloat16* Kb = Kg + base;
    const __hip_bfloat16* Vtb = Vtg + base;
    const int b = bh >> 4, h = bh & 15;

    __shared__ __align__(16) __hip_bfloat16 Pl[128 * 72];
    __hip_bfloat16* PrA = &Pl[w * 32 * 72];   // wave-private 16x64(+8 pad)
    __hip_bfloat16* PrB = PrA + 16 * 72;

    const int q0 = qi * 128;
    const int rowA = q0 + w * 16;             // chain A rows rowA..rowA+15
    const int rowB = rowA + 64;               // chain B rows

    bf16x8 qfA[2], qfB[2];
#pragma unroll
    for (int st = 0; st < 2; st++) {
        qfA[st] = *(const bf16x8*)(Qb + (size_t)(rowA + l15) * HD + st * 32 + quad * 8);
        qfB[st] = *(const bf16x8*)(Qb + (size_t)(rowB + l15) * HD + st * 32 + quad * 8);
    }

    bf16x8 ones;
#pragma unroll
    for (int i = 0; i < 8; i++) ones[i] = (short)0x3F80;  // bf16 1.0

    float mA[4], mB[4];
    f32x4 lA = {}, lB = {};
    f32x4 oA[4] = {}, oB[4] = {};
#pragma unroll
    for (int r = 0; r < 4; r++) { mA[r] = NEG_BIG; mB[r] = NEG_BIG; }

    bf16x8 kf[2][4];
    bf16x8 vf[2][4];
    LOAD_KF(0);  // prime K tile j=0

    // ---- full dual tiles: j = 0 .. 2qi-1, no masking ----
#pragma unroll 1
    for (int j = 0; j < 2 * qi; j++) {
        const int kv0 = j * 64;
        LOAD_VF(kv0);
        f32x4 scA[4] = {}, scB[4] = {};
        QK(scA, qfA);
        QK(scB, qfB);
        LOAD_KF(kv0 + 64);  // single-buffer refill; consumed next iter
        SMPV(scA, mA, lA, oA, PrA);
        SMPV(scB, mB, lB, oB, PrB);
    }

    // ---- j = 2qi: chain A diagonal, chain B full ----
    {
        const int kv0 = q0;
        LOAD_VF(kv0);
        f32x4 scA[4] = {}, scB[4] = {};
        QK(scA, qfA);
        QK(scB, qfB);
        LOAD_KF(kv0 + 64);
        MASK(scA, rowA, kv0);
        SMPV(scA, mA, lA, oA, PrA);
        SMPV(scB, mB, lB, oB, PrB);
    }

    // ---- j = 2qi+1: chain B diagonal only ----
    {
        const int kv0 = q0 + 64;
        LOAD_VF(kv0);
        f32x4 scB[4] = {};
        QK(scB, qfB);
        MASK(scB, rowB, kv0);
        SMPV(scB, mB, lB, oB, PrB);
    }

    // epilogue: O/l -> (B,S,D), both chains
#pragma unroll
    for (int t = 0; t < 4; t++)
#pragma unroll
        for (int r = 0; r < 4; r++) {
            int d = t * 16 + l15;
            int sA = rowA + quad * 4 + r;
            Og[((size_t)(b * S_LEN + sA)) * DM + h * HD + d] =
                __float2bfloat16(oA[t][r] / lA[r]);
            int sB = rowB + quad * 4 + r;
            Og[((size_t)(b * S_LEN + sB)) * DM + h * HD + d] =
                __float2bfloat16(oB[t][r] / lB[r]);
        }
}

// ---------------------------------------------------------------------------
// Output projection: out = attn @ Wo^T -> d_out as fp32 (bf16-rounded).
// Same global_load_lds staging as qkv.
// ---------------------------------------------------------------------------
__global__ __launch_bounds__(256) void oproj_kernel(
    const __hip_bfloat16* __restrict__ A,
    const __hip_bfloat16* __restrict__ W,
    float* __restrict__ out)
{
    __shared__ __align__(16) __hip_bfloat16 Asm[128 * 32];
    __shared__ __align__(16) __hip_bfloat16 Bsm[128 * 32];

    const int tid = threadIdx.x;
    const int wave = tid >> 6, lane = tid & 63;
    const int quad = lane >> 4, l15 = lane & 15;
    const int wm = (wave >> 1) * 64, wn = (wave & 1) * 64;
    const int m0 = blockIdx.y * 128, n0 = blockIdx.x * 128;

    f32x4 acc[4][4] = {};

    for (int k0 = 0; k0 < DM; k0 += 32) {
#pragma unroll
        for (int c = 0; c < 2; c++) {
            int idx = c * 2048 + tid * 8;
            int r = idx >> 5, kc = idx & 31;
            GLOAD_LDS16(A + (size_t)(m0 + r) * DM + k0 + kc, &Asm[idx]);
            GLOAD_LDS16(W + (size_t)(n0 + r) * DM + k0 + kc, &Bsm[idx]);
        }
        __syncthreads();
        bf16x8 af[4], bfv[4];
#pragma unroll
        for (int i = 0; i < 4; i++)
            af[i] = *(const bf16x8*)(&Asm[(wm + i * 16 + l15) * 32 + quad * 8]);
#pragma unroll
        for (int j = 0; j < 4; j++)
            bfv[j] = *(const bf16x8*)(&Bsm[(wn + j * 16 + l15) * 32 + quad * 8]);
#pragma unroll
        for (int i = 0; i < 4; i++)
#pragma unroll
            for (int j = 0; j < 4; j++)
                acc[i][j] = MFMA16(af[i], bfv[j], acc[i][j]);
        __syncthreads();
    }

#pragma unroll
    for (int i = 0; i < 4; i++)
#pragma unroll
        for (int r = 0; r < 4; r++) {
            int m = m0 + wm + i * 16 + quad * 4 + r;
#pragma unroll
            for (int j = 0; j < 4; j++) {
                int col = n0 + wn + j * 16 + l15;
                __hip_bfloat16 bb = __float2bfloat16(acc[i][j][r]);
                unsigned int u = ((unsigned int)(*(unsigned short*)&bb)) << 16;
                out[(size_t)m * DM + col] = __uint_as_float(u);
            }
        }
}

// ---------------------------------------------------------------------------
extern "C" void kernel_launch(void* const* d_in, const int* in_sizes, int n_in,
                              void* d_out, int out_size, void* d_ws, size_t ws_size,
                              hipStream_t stream)
{
    const float* x  = (const float*)d_in[0];
    const float* wq = (const float*)d_in[1];
    const float* wk = (const float*)d_in[2];
    const float* wv = (const float*)d_in[3];
    const float* wo = (const float*)d_in[4];
    float* out = (float*)d_out;

    const size_t xe = (size_t)2 * S_LEN * DM;
    const size_t we = (size_t)DM * DM;
    __hip_bfloat16* xb  = (__hip_bfloat16*)d_ws;
    __hip_bfloat16* wqb = xb + xe;
    __hip_bfloat16* wkb = wqb + we;
    __hip_bfloat16* wvb = wkb + we;
    __hip_bfloat16* wob = wvb + we;
    __hip_bfloat16* qws = wob + we;
    __hip_bfloat16* kws = qws + xe;
    __hip_bfloat16* vws = kws + xe;   // V^T (B,H,hd,S)
    __hip_bfloat16* aws = vws + xe;
    float2* tab = (float2*)aws;       // RoPE table: reuses attn_out region,
                                      // consumed (rope) before aws is written

    dim3 blk(256, 1, 1);
    convert_kernel<<<dim3(1024, 9, 1), blk, 0, stream>>>(x, wq, wk, wv, wo,
                                                         xb, wqb, wkb, wvb, wob, tab);
    qkv_kernel<<<dim3(8, 32, 3), blk, 0, stream>>>(xb, wqb, wkb, wvb, qws, kws, vws);
    rope_kernel<<<dim3(2048, 2, 1), blk, 0, stream>>>(qws, kws, tab);
    attn_kernel<<<dim3(32, 16, 1), blk, 0, stream>>>(qws, kws, vws, aws);
    oproj_kernel<<<dim3(8, 32, 1), blk, 0, stream>>>(aws, wob, out);
}